// Round 7
// baseline (560.594 us; speedup 1.0000x reference)
//
#include <hip/hip_runtime.h>
#include <hip/hip_bf16.h>

#define D 128

typedef __attribute__((ext_vector_type(8))) short bf16x8;
typedef __attribute__((ext_vector_type(4))) float f32x4;
typedef __attribute__((ext_vector_type(2))) float f32x2;
typedef __attribute__((ext_vector_type(2))) int int2v;

static __device__ __forceinline__ short f2bf(float f) {
  __hip_bfloat16 h = __float2bfloat16(f);
  return *reinterpret_cast<short*>(&h);
}

// ---- in-degree histogram over directed edges (both directions) ----
__global__ __launch_bounds__(256) void k_cnt(
    const int* __restrict__ s, const int* __restrict__ r,
    int* __restrict__ cnt, int E) {
  int i = blockIdx.x * 256 + threadIdx.x;
  if (i < E) {
    int sv = __builtin_nontemporal_load(s + i);
    int rv = __builtin_nontemporal_load(r + i);
    atomicAdd(&cnt[rv], 1);
    atomicAdd(&cnt[sv], 1);
  }
}

// ---- scan stage 1: per-2048-chunk exclusive scan + chunk totals ----
__global__ __launch_bounds__(256) void k_scan1(
    const int* __restrict__ cnt, int* __restrict__ rowptr,
    int* __restrict__ chsum, int N) {
  __shared__ int ts[256];
  int tid = threadIdx.x;
  int base = blockIdx.x * 2048 + tid * 8;
  int v[8];
  int run = 0;
#pragma unroll
  for (int j = 0; j < 8; ++j) {
    int idx = base + j;
    int t = (idx < N) ? cnt[idx] : 0;
    v[j] = run;
    run += t;
  }
  ts[tid] = run;
  __syncthreads();
  for (int off = 1; off < 256; off <<= 1) {
    int t = (tid >= off) ? ts[tid - off] : 0;
    __syncthreads();
    ts[tid] += t;
    __syncthreads();
  }
  int excl = ts[tid] - run;
#pragma unroll
  for (int j = 0; j < 8; ++j) {
    int idx = base + j;
    if (idx < N) rowptr[idx] = excl + v[j];
  }
  if (tid == 255) chsum[blockIdx.x] = ts[255];
}

// ---- scan stage 2: serial exclusive scan of chunk sums ----
__global__ __launch_bounds__(64) void k_scan2(int* __restrict__ chsum, int nch) {
  if (threadIdx.x == 0) {
    int run = 0;
    for (int i = 0; i < nch; ++i) { int t = chsum[i]; chsum[i] = run; run += t; }
    chsum[nch] = run;
  }
}

// ---- scan stage 3: add chunk offsets; init cursor; write rowptr[N] ----
__global__ __launch_bounds__(256) void k_scan3(
    int* __restrict__ rowptr, int* __restrict__ cursor,
    const int* __restrict__ chsum, int N, int nch) {
  int i = blockIdx.x * 256 + threadIdx.x;
  if (i < N) {
    int v = rowptr[i] + chsum[i >> 11];
    rowptr[i] = v;
    cursor[i] = v;
  } else if (i == N) {
    rowptr[N] = chsum[nch];
  }
}

// ---- fill CSR entries {src, raw e}; normalization applied later ----
__global__ __launch_bounds__(256) void k_fill(
    const int* __restrict__ s, const int* __restrict__ r,
    const float* __restrict__ e,
    int* __restrict__ cursor, int2v* __restrict__ ent, int E) {
  int i = blockIdx.x * 256 + threadIdx.x;
  if (i >= E) return;
  int sv = __builtin_nontemporal_load(s + i);
  int rv = __builtin_nontemporal_load(r + i);
  float ev = __builtin_nontemporal_load(e + i);
  int ey = __float_as_int(ev);
  int p1 = atomicAdd(&cursor[rv], 1);
  int2v v1; v1.x = sv; v1.y = ey;
  __builtin_nontemporal_store(v1, ent + p1);
  int p2 = atomicAdd(&cursor[sv], 1);
  int2v v2; v2.x = rv; v2.y = ey;
  __builtin_nontemporal_store(v2, ent + p2);
}

// ---- weighted degree from CSR (no atomics): wave per node, shfl reduce ----
__global__ __launch_bounds__(256) void k_degdis(
    const int* __restrict__ rowptr, const int2v* __restrict__ ent,
    float* __restrict__ dis, int N) {
  int node = blockIdx.x * 4 + (threadIdx.x >> 6);
  int lane = threadIdx.x & 63;
  if (node >= N) return;
  int beg = rowptr[node], end = rowptr[node + 1];
  float sum = 0.f;
  for (int j = beg + lane; j < end; j += 64)
    sum += __int_as_float(ent[j].y);
#pragma unroll
  for (int off = 32; off; off >>= 1) sum += __shfl_xor(sum, off, 64);
  if (lane == 0) dis[node] = sum > 0.f ? rsqrtf(sum) : 0.f;
}

// ---- normalize entry weights: ent[j].w = dis[node] * e * dis[src] ----
__global__ __launch_bounds__(256) void k_normw(
    const int* __restrict__ rowptr, int2v* __restrict__ ent,
    const float* __restrict__ dis, int N) {
  int node = blockIdx.x * 4 + (threadIdx.x >> 6);
  int lane = threadIdx.x & 63;
  if (node >= N) return;
  float dself = dis[node];
  int beg = rowptr[node], end = rowptr[node + 1];
  for (int j = beg + lane; j < end; j += 64) {
    int2v v = ent[j];
    float w = dself * __int_as_float(v.y) * dis[v.x];
    v.y = __float_as_int(w);
    ent[j] = v;
  }
}

// ---- W prep for both layers: Wt[col*128+k] = bf16(W[k][col]) ----
__global__ __launch_bounds__(256) void k_wprep2(
    const float* __restrict__ W1, const float* __restrict__ W2,
    unsigned short* __restrict__ Wt1, unsigned short* __restrict__ Wt2) {
  int idx = blockIdx.x * 256 + threadIdx.x;   // 0 .. 2*D*D
  const float* W = (idx < D * D) ? W1 : W2;
  unsigned short* Wt = (idx < D * D) ? Wt1 : Wt2;
  int t = idx & (D * D - 1);
  int col = t >> 7, k = t & 127;
  Wt[t] = (unsigned short)f2bf(W[k * D + col]);
}

// ---- Y = bf16(X @ W) via MFMA. Block: 64 rows x 128 cols, 4 waves. ----
__global__ __launch_bounds__(256) void k_gemm_mfma(
    const float* __restrict__ X, const unsigned short* __restrict__ Wt,
    unsigned short* __restrict__ Y, int nrows) {
  __shared__ unsigned short wl[128 * 128];  // 32 KB, swizzled
  int tid = threadIdx.x;
  {
    const int4* src = reinterpret_cast<const int4*>(Wt);
#pragma unroll
    for (int j = 0; j < 8; ++j) {
      int c = tid + 256 * j;            // 16B chunk id, 2048 total
      int4 v = src[c];
      int byte = c * 16;
      int col = byte >> 8;              // row stride 256 B
      int swz = byte ^ ((col & 7) << 4);
      *reinterpret_cast<int4*>(reinterpret_cast<char*>(wl) + swz) = v;
    }
  }
  __syncthreads();

  int lane = tid & 63;
  int wv = tid >> 6;                    // wave 0..3
  int lr = lane & 15;
  int kgrp = lane >> 4;                 // 0..3
  int row = blockIdx.x * 64 + wv * 16 + lr;
  bool valid = row < nrows;

  f32x4 acc[8];
#pragma unroll
  for (int n = 0; n < 8; ++n) acc[n] = (f32x4){0.f, 0.f, 0.f, 0.f};

#pragma unroll
  for (int ks = 0; ks < 4; ++ks) {
    bf16x8 a;
    if (valid) {
      const float4* xp = reinterpret_cast<const float4*>(
          X + (size_t)row * D + ks * 32 + kgrp * 8);
      float4 f0 = xp[0], f1 = xp[1];
      a[0] = f2bf(f0.x); a[1] = f2bf(f0.y); a[2] = f2bf(f0.z); a[3] = f2bf(f0.w);
      a[4] = f2bf(f1.x); a[5] = f2bf(f1.y); a[6] = f2bf(f1.z); a[7] = f2bf(f1.w);
    } else {
      a = (bf16x8){0, 0, 0, 0, 0, 0, 0, 0};
    }
#pragma unroll
    for (int n = 0; n < 8; ++n) {
      int col = n * 16 + lr;
      int byte = col * 256 + ks * 64 + kgrp * 16;
      int swz = byte ^ ((col & 7) << 4);
      bf16x8 b = *reinterpret_cast<const bf16x8*>(
          reinterpret_cast<const char*>(wl) + swz);
      acc[n] = __builtin_amdgcn_mfma_f32_16x16x32_bf16(a, b, acc[n], 0, 0, 0);
    }
  }

  // C/D layout: D[(lane>>4)*4 + i][lane&15] in acc[n][i]
  int r0 = blockIdx.x * 64 + wv * 16 + kgrp * 4;
#pragma unroll
  for (int n = 0; n < 8; ++n) {
    int col = n * 16 + lr;
#pragma unroll
    for (int i = 0; i < 4; ++i) {
      int rr = r0 + i;
      if (rr < nrows) Y[(size_t)rr * D + col] = (unsigned short)f2bf(acc[n][i]);
    }
  }
}

// ---- gather-aggregate: one 64-lane wave per node, 2 dims/lane (bf16x2) ----
// out[v,:] = prev[v,:] + b[:] + sum_{edges into v} X[src,:] * w
// Edge loop unrolled x8 for MLP; streams (prev/ent/out) nontemporal so the
// L2 keeps the X table (25.6 MB) resident for the gathers.
__global__ __launch_bounds__(256) void k_agg(
    const int* __restrict__ rowptr, const int2v* __restrict__ ent,
    const unsigned int* __restrict__ X2, const float* __restrict__ prev,
    const float* __restrict__ bias, float* __restrict__ out, int N) {
  int node = blockIdx.x * 4 + (threadIdx.x >> 6);
  int lane = threadIdx.x & 63;
  if (node >= N) return;
  f32x2 pv = __builtin_nontemporal_load(
      reinterpret_cast<const f32x2*>(prev) + (size_t)node * 64 + lane);
  float2 bb = reinterpret_cast<const float2*>(bias)[lane];
  float ax = pv.x + bb.x, ay = pv.y + bb.y;
  int beg = rowptr[node], end = rowptr[node + 1];
  int j = beg;
  for (; j + 8 <= end; j += 8) {
    int2v ee[8];
#pragma unroll
    for (int u = 0; u < 8; ++u) ee[u] = __builtin_nontemporal_load(ent + j + u);
    unsigned int xz[8];
#pragma unroll
    for (int u = 0; u < 8; ++u) xz[u] = X2[(size_t)ee[u].x * 64 + lane];
#pragma unroll
    for (int u = 0; u < 8; ++u) {
      float w = __int_as_float(ee[u].y);
      ax = fmaf(__uint_as_float(xz[u] << 16), w, ax);
      ay = fmaf(__uint_as_float(xz[u] & 0xffff0000u), w, ay);
    }
  }
  for (; j < end; ++j) {
    int2v eJ = ent[j];
    float w = __int_as_float(eJ.y);
    unsigned int xz = X2[(size_t)eJ.x * 64 + lane];
    ax = fmaf(__uint_as_float(xz << 16), w, ax);
    ay = fmaf(__uint_as_float(xz & 0xffff0000u), w, ay);
  }
  f32x2 res; res.x = ax; res.y = ay;
  __builtin_nontemporal_store(
      res, reinterpret_cast<f32x2*>(out) + (size_t)node * 64 + lane);
}

extern "C" void kernel_launch(void* const* d_in, const int* in_sizes, int n_in,
                              void* d_out, int out_size, void* d_ws, size_t ws_size,
                              hipStream_t stream) {
  const float* nodes     = (const float*)d_in[0];
  const int*   senders   = (const int*)d_in[1];
  const int*   receivers = (const int*)d_in[2];
  const float* edges     = (const float*)d_in[3];
  const float* W1        = (const float*)d_in[4];
  const float* b1        = (const float*)d_in[5];
  const float* W2        = (const float*)d_in[6];
  const float* b2        = (const float*)d_in[7];
  float* out = (float*)d_out;

  int N = in_sizes[0] / D;
  int E = in_sizes[1];
  int NCH = (N + 2047) / 2048;

  // workspace layout (512-B aligned slabs)
  auto alignup = [](size_t x) { return (x + 511) / 512 * 512; };
  char* p = (char*)d_ws;
  float* dis    = (float*)p; p += alignup((size_t)N * 4);
  int*   cnt    = (int*)p;   p += alignup((size_t)N * 4);
  int*   rowptr = (int*)p;   p += alignup(((size_t)N + 1) * 4);
  int*   cursor = (int*)p;   p += alignup((size_t)N * 4);
  int*   chsum  = (int*)p;   p += alignup(((size_t)NCH + 1) * 4);
  int2v* ent    = (int2v*)p; p += alignup((size_t)2 * E * 8);
  unsigned short* Wt1 = (unsigned short*)p; p += alignup((size_t)D * D * 2);
  unsigned short* Wt2 = (unsigned short*)p; p += alignup((size_t)D * D * 2);
  unsigned short* X   = (unsigned short*)p;  // N*D bf16 = 25.6 MB

  hipMemsetAsync(cnt, 0, (size_t)N * 4, stream);

  int eb = (E + 255) / 256;
  int nb4 = (N + 3) / 4;

  // CSR build (shared by both layers); only int atomics remain
  k_cnt<<<eb, 256, 0, stream>>>(senders, receivers, cnt, E);
  k_scan1<<<NCH, 256, 0, stream>>>(cnt, rowptr, chsum, N);
  k_scan2<<<1, 64, 0, stream>>>(chsum, NCH);
  k_scan3<<<(N + 1 + 255) / 256, 256, 0, stream>>>(rowptr, cursor, chsum, N, NCH);
  k_fill<<<eb, 256, 0, stream>>>(senders, receivers, edges, cursor, ent, E);

  // weighted degree + normalization from CSR (atomic-free)
  k_degdis<<<nb4, 256, 0, stream>>>(rowptr, ent, dis, N);
  k_normw<<<nb4, 256, 0, stream>>>(rowptr, ent, dis, N);

  // weight prep (bf16, transposed), both layers in one launch
  k_wprep2<<<(2 * D * D) / 256, 256, 0, stream>>>(W1, W2, Wt1, Wt2);

  int gemm_blocks = (N + 63) / 64;

  // ---- layer 1: out = nodes + b1 + Agg(nodes @ W1) ----
  k_gemm_mfma<<<gemm_blocks, 256, 0, stream>>>(nodes, Wt1, X, N);
  k_agg<<<nb4, 256, 0, stream>>>(rowptr, ent, (const unsigned int*)X,
                                 nodes, b1, out, N);

  // ---- layer 2: out = h1 + b2 + Agg(h1 @ W2), h1 = out (in-place safe) ----
  k_gemm_mfma<<<gemm_blocks, 256, 0, stream>>>(out, Wt2, X, N);
  k_agg<<<nb4, 256, 0, stream>>>(rowptr, ent, (const unsigned int*)X,
                                 out, b2, out, N);
}